// Round 2
// baseline (224.680 us; speedup 1.0000x reference)
//
#include <hip/hip_runtime.h>
#include <math.h>

#define C_ 8
#define B_ 4
#define T_ 4096
#define D_ 128
#define TT 64
#define NCH (T_ / TT)                       // 64 chunks
#define CBTD ((size_t)C_ * B_ * T_ * D_)    // 16777216
#define SSIZE ((size_t)2 * C_ * B_ * NCH * D_)  // 524288 floats

__device__ __forceinline__ float lam_of(int c) {
  // matches python: 1 - 2**(-(c * log2(8192)/7)) computed in double
  return (float)(1.0 - exp2(-(double)c * (13.0 / 7.0)));
}

// lam^n, safe for lam==0 (n==0 -> 1, n>0 -> 0), n>=0
__device__ __forceinline__ float decay_pow(float lam, float l2lam, int n) {
  if (n == 0) return 1.0f;
  if (lam == 0.0f) return 0.0f;
  return exp2f((float)n * l2lam);
}

// Phase A: per (c,b,64-t tile): logits = z*W + b (both dirs), v = sigmoid*z,
// write v to d_out (scratch), and chunk decayed sum S to ws.
__global__ __launch_bounds__(512, 1)
void gate_local_kernel(const float* __restrict__ z,
                       const float* __restrict__ Wf, const float* __restrict__ bf,
                       const float* __restrict__ Wb, const float* __restrict__ bb,
                       float* __restrict__ out, float* __restrict__ S) {
  __shared__ float zT[D_][TT + 4];   // transposed z tile, pad keeps b128 align + no conflicts
  __shared__ float Wl[D_][D_];       // 64 KB, one direction at a time
  __shared__ float red[16][D_];      // S reduction across t-groups

  const int bi = blockIdx.x;
  const int tile = bi & (NCH - 1);
  const int b = (bi >> 6) & (B_ - 1);
  const int c = bi >> 8;
  const int t0g = tile * TT;
  const int tid = threadIdx.x;

  const float lam = lam_of(c);
  const float l2lam = (lam > 0.f) ? log2f(lam) : 0.f;

  const float* zsrc = z + ((size_t)(c * B_ + b) * T_ + t0g) * D_;

  // load + transpose z tile (coalesced float4 reads)
  for (int i = 0; i < 4; ++i) {
    int fidx = tid + i * 512;      // 0..2047 float4 chunks (64 t x 32 d4)
    int t = fidx >> 5;
    int d4 = (fidx & 31) * 4;
    float4 v = *(const float4*)(zsrc + (size_t)t * D_ + d4);
    zT[d4 + 0][t] = v.x;
    zT[d4 + 1][t] = v.y;
    zT[d4 + 2][t] = v.z;
    zT[d4 + 3][t] = v.w;
  }

  const int te_t = tid >> 5;     // 0..15 -> t sub-tile
  const int te_e = tid & 31;     // 0..31 -> e sub-tile
  const int tt0 = te_t * 4;
  const int e0 = te_e * 4;

  for (int dir = 0; dir < 2; ++dir) {
    const float* Wsrc = (dir ? Wb : Wf) + (size_t)c * D_ * D_;
    const float* bias = (dir ? bb : bf) + (size_t)c * D_;

    __syncthreads();   // zT ready / Wl+red free for reuse
    for (int i = 0; i < 8; ++i) {
      int fidx = tid + i * 512;    // 0..4095 float4 chunks (128 d x 32 e4)
      int d = fidx >> 5;
      int e4 = (fidx & 31) * 4;
      *(float4*)&Wl[d][e4] = *(const float4*)(Wsrc + (size_t)d * D_ + e4);
    }
    __syncthreads();

    float acc[4][4] = {{0.f,0.f,0.f,0.f},{0.f,0.f,0.f,0.f},
                       {0.f,0.f,0.f,0.f},{0.f,0.f,0.f,0.f}};
    #pragma unroll 4
    for (int d = 0; d < D_; ++d) {
      const float4 zv = *(const float4*)&zT[d][tt0];
      const float4 wv = *(const float4*)&Wl[d][e0];
      acc[0][0] = fmaf(zv.x, wv.x, acc[0][0]);
      acc[0][1] = fmaf(zv.x, wv.y, acc[0][1]);
      acc[0][2] = fmaf(zv.x, wv.z, acc[0][2]);
      acc[0][3] = fmaf(zv.x, wv.w, acc[0][3]);
      acc[1][0] = fmaf(zv.y, wv.x, acc[1][0]);
      acc[1][1] = fmaf(zv.y, wv.y, acc[1][1]);
      acc[1][2] = fmaf(zv.y, wv.z, acc[1][2]);
      acc[1][3] = fmaf(zv.y, wv.w, acc[1][3]);
      acc[2][0] = fmaf(zv.z, wv.x, acc[2][0]);
      acc[2][1] = fmaf(zv.z, wv.y, acc[2][1]);
      acc[2][2] = fmaf(zv.z, wv.z, acc[2][2]);
      acc[2][3] = fmaf(zv.z, wv.w, acc[2][3]);
      acc[3][0] = fmaf(zv.w, wv.x, acc[3][0]);
      acc[3][1] = fmaf(zv.w, wv.y, acc[3][1]);
      acc[3][2] = fmaf(zv.w, wv.z, acc[3][2]);
      acc[3][3] = fmaf(zv.w, wv.w, acc[3][3]);
    }

    const float4 bv = *(const float4*)(bias + e0);
    const float bvv[4] = {bv.x, bv.y, bv.z, bv.w};
    float* dst = out + (size_t)dir * CBTD +
                 ((size_t)(c * B_ + b) * T_ + t0g) * D_;
    float part[4] = {0.f, 0.f, 0.f, 0.f};

    #pragma unroll
    for (int i = 0; i < 4; ++i) {
      const int t = tt0 + i;
      const int nexp = dir ? t : (TT - 1 - t);   // decay distance to chunk terminal
      const float wdec = decay_pow(lam, l2lam, nexp);
      float vo[4];
      #pragma unroll
      for (int j = 0; j < 4; ++j) {
        const float logit = acc[i][j] + bvv[j];
        const float g = 1.0f / (1.0f + expf(-logit));
        vo[j] = g * zT[e0 + j][t];
      }
      float4 o4 = make_float4(vo[0], vo[1], vo[2], vo[3]);
      *(float4*)(dst + (size_t)t * D_ + e0) = o4;
      #pragma unroll
      for (int j = 0; j < 4; ++j) part[j] = fmaf(wdec, vo[j], part[j]);
    }

    #pragma unroll
    for (int j = 0; j < 4; ++j) red[te_t][e0 + j] = part[j];
    __syncthreads();
    if (tid < D_) {
      float s = 0.f;
      #pragma unroll
      for (int k = 0; k < 16; ++k) s += red[k][tid];
      S[(((size_t)(dir * C_ + c) * B_ + b) * NCH + tile) * D_ + tid] = s;
    }
  }
}

// Phase B: carry prefix across chunks (tiny)
__global__ __launch_bounds__(128)
void prefix_kernel(const float* __restrict__ S, float* __restrict__ Cin) {
  const int bi = blockIdx.x;        // (dir, c, b)
  const int dir = bi >> 5;
  const int c = (bi >> 2) & 7;
  const int b = bi & 3;
  const int e = threadIdx.x;
  const float lam = lam_of(c);
  const float l2lam = (lam > 0.f) ? log2f(lam) : 0.f;
  const float lamL = decay_pow(lam, l2lam, TT);
  const size_t base = ((size_t)(dir * C_ + c) * B_ + b) * NCH * D_ + e;
  float cin = 0.f;
  if (dir == 0) {
    for (int k = 0; k < NCH; ++k) {
      Cin[base + (size_t)k * D_] = cin;
      cin = fmaf(lamL, cin, S[base + (size_t)k * D_]);
    }
  } else {
    for (int k = NCH - 1; k >= 0; --k) {
      Cin[base + (size_t)k * D_] = cin;
      cin = fmaf(lamL, cin, S[base + (size_t)k * D_]);
    }
  }
}

// Phase C: in-place chunk scan seeded with carry
__global__ __launch_bounds__(128)
void scan_kernel(float* __restrict__ out, const float* __restrict__ Cin) {
  const int bi = blockIdx.x;          // ((dir*C + c)*B + b)*NCH + k
  const int k = bi & (NCH - 1);
  const int b = (bi >> 6) & 3;
  const int c = (bi >> 8) & 7;
  const int dir = bi >> 11;
  const int e = threadIdx.x;
  const float lam = lam_of(c);
  float h = Cin[(((size_t)(dir * C_ + c) * B_ + b) * NCH + k) * D_ + e];
  float* reg = out + (size_t)dir * CBTD + (size_t)(c * B_ + b) * T_ * D_ + e;
  if (dir == 0) {
    for (int i = 0; i < TT; ++i) {
      const size_t o = (size_t)(k * TT + i) * D_;
      h = fmaf(lam, h, reg[o]);
      reg[o] = h;
    }
  } else {
    for (int i = TT - 1; i >= 0; --i) {
      const size_t o = (size_t)(k * TT + i) * D_;
      h = fmaf(lam, h, reg[o]);
      reg[o] = h;
    }
  }
}

extern "C" void kernel_launch(void* const* d_in, const int* in_sizes, int n_in,
                              void* d_out, int out_size, void* d_ws, size_t ws_size,
                              hipStream_t stream) {
  const float* z  = (const float*)d_in[0];
  const float* Wf = (const float*)d_in[1];
  const float* bf = (const float*)d_in[2];
  const float* Wb = (const float*)d_in[3];
  const float* bb = (const float*)d_in[4];
  float* out = (float*)d_out;
  float* S   = (float*)d_ws;          // 2 MB
  float* Cin = S + SSIZE;             // 2 MB

  gate_local_kernel<<<dim3(C_ * B_ * NCH), dim3(512), 0, stream>>>(
      z, Wf, bf, Wb, bb, out, S);
  prefix_kernel<<<dim3(2 * C_ * B_), dim3(128), 0, stream>>>(S, Cin);
  scan_kernel<<<dim3(2 * C_ * B_ * NCH), dim3(128), 0, stream>>>(out, Cin);
}

// Round 3
// 137.497 us; speedup vs baseline: 1.6341x; 1.6341x over previous
//
#include <hip/hip_runtime.h>
#include <math.h>

#define C_ 8
#define B_ 4
#define T_ 4096
#define D_ 128
#define TT 64
#define NCH (T_ / TT)                       // 64 chunks
#define CBTD ((size_t)C_ * B_ * T_ * D_)    // 16777216
#define SSIZE ((size_t)2 * C_ * B_ * NCH * D_)  // 524288 floats

typedef __attribute__((ext_vector_type(8))) short short8;
typedef __attribute__((ext_vector_type(4))) float f32x4;

__device__ __forceinline__ float lam_of(int c) {
  return (float)(1.0 - exp2(-(double)c * (13.0 / 7.0)));
}

__device__ __forceinline__ float decay_pow(float lam, float l2lam, int n) {
  if (n == 0) return 1.0f;
  if (lam == 0.0f) return 0.0f;
  return exp2f((float)n * l2lam);
}

__device__ __forceinline__ unsigned short f2bf(float x) {
  unsigned u = __float_as_uint(x);
  unsigned r = (u + 0x7FFFu + ((u >> 16) & 1u)) >> 16;   // RNE
  return (unsigned short)r;
}

// ---- pre-kernel: W (f32 [dir][c][d][e]) -> bf16 transposed Wt[dir*8+c][e][d]
__global__ __launch_bounds__(256)
void wcvt_kernel(const float* __restrict__ Wf, const float* __restrict__ Wb,
                 unsigned short* __restrict__ Wt) {
  __shared__ unsigned short Tq[128][130];
  const int blk = blockIdx.x;          // dir*8 + c
  const float* src = ((blk & 8) ? Wb : Wf) + (size_t)(blk & 7) * D_ * D_;
  const int tid = threadIdx.x;
  for (int i = 0; i < 16; ++i) {
    int fidx = tid + 256 * i;          // 4096 float4 chunks
    int d = fidx >> 5, e4 = (fidx & 31) * 4;
    float4 v = *(const float4*)(src + (size_t)d * D_ + e4);
    Tq[e4 + 0][d] = f2bf(v.x);
    Tq[e4 + 1][d] = f2bf(v.y);
    Tq[e4 + 2][d] = f2bf(v.z);
    Tq[e4 + 3][d] = f2bf(v.w);
  }
  __syncthreads();
  unsigned short* dst = Wt + (size_t)blk * D_ * D_;
  for (int i = 0; i < 8; ++i) {
    int fidx = tid + 256 * i;          // 2048 chunks of 8 bf16
    int e = fidx >> 4, d8 = (fidx & 15) * 8;
    unsigned short tmp[8];
    #pragma unroll
    for (int q = 0; q < 8; ++q) tmp[q] = Tq[e][d8 + q];
    #pragma unroll
    for (int q = 0; q < 8; ++q) dst[(size_t)e * D_ + d8 + q] = tmp[q];
  }
}

// ---- Phase A: MFMA gate + v + chunk-terminal decayed sums
__global__ __launch_bounds__(256)
void gate_mfma_kernel(const float* __restrict__ z,
                      const unsigned short* __restrict__ Wt,
                      const float* __restrict__ bf, const float* __restrict__ bb,
                      float* __restrict__ out, float* __restrict__ S) {
  __shared__ unsigned short zb[64 * 128];   // bf16 A tile, XOR-swizzled (16 KB)
  __shared__ float zf[64][128];             // f32 copy for epilogue (32 KB)
  __shared__ float red[16][128];            // S reduction (8 KB)

  const int bi = blockIdx.x;
  const int tile = bi & (NCH - 1);
  const int b = (bi >> 6) & (B_ - 1);
  const int c = bi >> 8;
  const int tid = threadIdx.x;
  const int lane = tid & 63;
  const int w = tid >> 6;                   // wave 0..3 -> t-rows w*16..w*16+15
  const int l15 = lane & 15;
  const int l4 = lane >> 4;

  const float* zsrc = z + ((size_t)(c * B_ + b) * T_ + tile * TT) * D_;

  // stage z: f32 copy + swizzled bf16 copy
  for (int i = 0; i < 8; ++i) {
    int fidx = tid + 256 * i;               // 2048 float4
    int row = fidx >> 5, col4 = (fidx & 31) * 4;
    float4 v = *(const float4*)(zsrc + (size_t)row * D_ + col4);
    *(float4*)&zf[row][col4] = v;
    unsigned short p[4] = {f2bf(v.x), f2bf(v.y), f2bf(v.z), f2bf(v.w)};
    int cb = col4 * 2;                      // byte col 0..255 (8B granule)
    int slot = cb >> 4, rem = cb & 15;
    int addr = row * 256 + (((slot ^ (row & 15)) << 4) | rem);
    *(uint2*)((char*)zb + addr) = *(const uint2*)p;
  }
  __syncthreads();

  // A-fragments: lane holds A[m=l15][k=8*l4+j], k-chunk ks*32
  short8 afrag[4];
  const int rowA = w * 16 + l15;
  #pragma unroll
  for (int ks = 0; ks < 4; ++ks) {
    int slot = ks * 4 + l4;
    int addr = rowA * 256 + (((slot ^ (rowA & 15)) << 4));
    afrag[ks] = *(const short8*)((const char*)zb + addr);
  }

  const float lam = lam_of(c);
  const float l2lam = (lam > 0.f) ? log2f(lam) : 0.f;

  for (int dir = 0; dir < 2; ++dir) {
    const unsigned short* wt = Wt + (size_t)(dir * 8 + c) * D_ * D_;
    const float* bias = (dir ? bb : bf) + (size_t)c * D_;

    float wdec[4];
    #pragma unroll
    for (int r = 0; r < 4; ++r) {
      int row = w * 16 + l4 * 4 + r;
      int nexp = dir ? row : (TT - 1 - row);
      wdec[r] = decay_pow(lam, l2lam, nexp);
    }

    f32x4 acc[8];
    #pragma unroll
    for (int f = 0; f < 8; ++f) acc[f] = (f32x4){0.f, 0.f, 0.f, 0.f};

    #pragma unroll
    for (int f = 0; f < 8; ++f) {
      const unsigned short* wb_ = wt + (size_t)(f * 16 + l15) * D_ + l4 * 8;
      #pragma unroll
      for (int ks = 0; ks < 4; ++ks) {
        short8 bfrag = *(const short8*)(wb_ + ks * 32);
        acc[f] = __builtin_amdgcn_mfma_f32_16x16x32_bf16(afrag[ks], bfrag, acc[f], 0, 0, 0);
      }
    }

    float* dst = out + (size_t)dir * CBTD +
                 ((size_t)(c * B_ + b) * T_ + tile * TT) * D_;

    __syncthreads();   // previous dir's S-read of red is done before rewrite
    #pragma unroll
    for (int f = 0; f < 8; ++f) {
      int col = f * 16 + l15;
      float bcol = bias[col];
      float p = 0.f;
      #pragma unroll
      for (int r = 0; r < 4; ++r) {
        int row = w * 16 + l4 * 4 + r;
        float logit = acc[f][r] + bcol;
        float g = 1.0f / (1.0f + __expf(-logit));
        float v = g * zf[row][col];
        dst[(size_t)row * D_ + col] = v;
        p = fmaf(wdec[r], v, p);
      }
      red[w * 4 + l4][col] = p;
    }
    __syncthreads();
    if (tid < 128) {
      float s = 0.f;
      #pragma unroll
      for (int k = 0; k < 16; ++k) s += red[k][tid];
      S[(((size_t)(dir * C_ + c) * B_ + b) * NCH + tile) * D_ + tid] = s;
    }
  }
}

// ---- Phase B: carry prefix across chunks (tiny)
__global__ __launch_bounds__(128)
void prefix_kernel(const float* __restrict__ S, float* __restrict__ Cin) {
  const int bi = blockIdx.x;        // (dir, c, b)
  const int dir = bi >> 5;
  const int c = (bi >> 2) & 7;
  const int b = bi & 3;
  const int e = threadIdx.x;
  const float lam = lam_of(c);
  const float l2lam = (lam > 0.f) ? log2f(lam) : 0.f;
  const float lamL = decay_pow(lam, l2lam, TT);
  const size_t base = ((size_t)(dir * C_ + c) * B_ + b) * NCH * D_ + e;
  float cin = 0.f;
  if (dir == 0) {
    for (int k = 0; k < NCH; ++k) {
      Cin[base + (size_t)k * D_] = cin;
      cin = fmaf(lamL, cin, S[base + (size_t)k * D_]);
    }
  } else {
    for (int k = NCH - 1; k >= 0; --k) {
      Cin[base + (size_t)k * D_] = cin;
      cin = fmaf(lamL, cin, S[base + (size_t)k * D_]);
    }
  }
}

// ---- Phase C: in-place chunk scan seeded with carry
__global__ __launch_bounds__(128)
void scan_kernel(float* __restrict__ out, const float* __restrict__ Cin) {
  const int bi = blockIdx.x;          // ((dir*C + c)*B + b)*NCH + k
  const int k = bi & (NCH - 1);
  const int b = (bi >> 6) & 3;
  const int c = (bi >> 8) & 7;
  const int dir = bi >> 11;
  const int e = threadIdx.x;
  const float lam = lam_of(c);
  float h = Cin[(((size_t)(dir * C_ + c) * B_ + b) * NCH + k) * D_ + e];
  float* reg = out + (size_t)dir * CBTD + (size_t)(c * B_ + b) * T_ * D_ + e;
  if (dir == 0) {
    for (int i = 0; i < TT; ++i) {
      const size_t o = (size_t)(k * TT + i) * D_;
      h = fmaf(lam, h, reg[o]);
      reg[o] = h;
    }
  } else {
    for (int i = TT - 1; i >= 0; --i) {
      const size_t o = (size_t)(k * TT + i) * D_;
      h = fmaf(lam, h, reg[o]);
      reg[o] = h;
    }
  }
}

extern "C" void kernel_launch(void* const* d_in, const int* in_sizes, int n_in,
                              void* d_out, int out_size, void* d_ws, size_t ws_size,
                              hipStream_t stream) {
  const float* z  = (const float*)d_in[0];
  const float* Wf = (const float*)d_in[1];
  const float* bf = (const float*)d_in[2];
  const float* Wb = (const float*)d_in[3];
  const float* bb = (const float*)d_in[4];
  float* out = (float*)d_out;
  float* S   = (float*)d_ws;                      // 2 MB
  float* Cin = S + SSIZE;                         // 2 MB
  unsigned short* Wt = (unsigned short*)(Cin + SSIZE);  // 512 KB bf16

  wcvt_kernel<<<dim3(16), dim3(256), 0, stream>>>(Wf, Wb, Wt);
  gate_mfma_kernel<<<dim3(C_ * B_ * NCH), dim3(256), 0, stream>>>(
      z, Wt, bf, bb, out, S);
  prefix_kernel<<<dim3(2 * C_ * B_), dim3(128), 0, stream>>>(S, Cin);
  scan_kernel<<<dim3(2 * C_ * B_ * NCH), dim3(128), 0, stream>>>(out, Cin);
}

// Round 4
// 132.511 us; speedup vs baseline: 1.6956x; 1.0376x over previous
//
#include <hip/hip_runtime.h>
#include <math.h>

#define C_ 8
#define B_ 4
#define T_ 4096
#define D_ 128
#define TT 64
#define NCH (T_ / TT)                       // 64 chunks
#define CBTD ((size_t)C_ * B_ * T_ * D_)    // 16777216
#define SSIZE ((size_t)2 * C_ * B_ * NCH * D_)  // 524288 floats

typedef __attribute__((ext_vector_type(8))) short short8;
typedef __attribute__((ext_vector_type(4))) float f32x4;

__device__ __forceinline__ float lam_of(int c) {
  return (float)(1.0 - exp2(-(double)c * (13.0 / 7.0)));
}

__device__ __forceinline__ float decay_pow(float lam, float l2lam, int n) {
  if (n == 0) return 1.0f;
  if (lam == 0.0f) return 0.0f;
  return exp2f((float)n * l2lam);
}

__device__ __forceinline__ unsigned short f2bf(float x) {
  unsigned u = __float_as_uint(x);
  unsigned r = (u + 0x7FFFu + ((u >> 16) & 1u)) >> 16;   // RNE
  return (unsigned short)r;
}

// ---- pre-kernel: W (f32 [dir][c][d][e]) -> bf16 transposed Wt[dir*8+c][e][d]
__global__ __launch_bounds__(256)
void wcvt_kernel(const float* __restrict__ Wf, const float* __restrict__ Wb,
                 unsigned short* __restrict__ Wt) {
  __shared__ unsigned short Tq[128][130];
  const int blk = blockIdx.x;          // dir*8 + c
  const float* src = ((blk & 8) ? Wb : Wf) + (size_t)(blk & 7) * D_ * D_;
  const int tid = threadIdx.x;
  for (int i = 0; i < 16; ++i) {
    int fidx = tid + 256 * i;          // 4096 float4 chunks
    int d = fidx >> 5, e4 = (fidx & 31) * 4;
    float4 v = *(const float4*)(src + (size_t)d * D_ + e4);
    Tq[e4 + 0][d] = f2bf(v.x);
    Tq[e4 + 1][d] = f2bf(v.y);
    Tq[e4 + 2][d] = f2bf(v.z);
    Tq[e4 + 3][d] = f2bf(v.w);
  }
  __syncthreads();
  unsigned short* dst = Wt + (size_t)blk * D_ * D_;
  for (int i = 0; i < 8; ++i) {
    int fidx = tid + 256 * i;          // 2048 chunks of 8 bf16
    int e = fidx >> 4, d8 = (fidx & 15) * 8;
    unsigned short tmp[8];
    #pragma unroll
    for (int q = 0; q < 8; ++q) tmp[q] = Tq[e][d8 + q];
    #pragma unroll
    for (int q = 0; q < 8; ++q) dst[(size_t)e * D_ + d8 + q] = tmp[q];
  }
}

// ---- Phase A: MFMA gate + in-chunk local scan; writes local_h to out, chunk terminal to S
__global__ __launch_bounds__(256, 3)
void gate_mfma_kernel(const float* __restrict__ z,
                      const unsigned short* __restrict__ Wt,
                      const float* __restrict__ bf, const float* __restrict__ bb,
                      float* __restrict__ out, float* __restrict__ S) {
  __shared__ float zf[64][132];    // z tile f32, padded (33.8 KB)
  __shared__ float term[16][132];  // group terminals -> group carries (8.4 KB)

  const int bi = blockIdx.x;
  const int tile = bi & (NCH - 1);
  const int b = (bi >> 6) & (B_ - 1);
  const int c = bi >> 8;
  const int tid = threadIdx.x;
  const int lane = tid & 63;
  const int w = tid >> 6;          // wave -> rows w*16..w*16+15
  const int l15 = lane & 15;
  const int l4 = lane >> 4;

  const float lam = lam_of(c);
  float lp[5];                     // lam^0..lam^4
  lp[0] = 1.f;
  #pragma unroll
  for (int i = 1; i < 5; ++i) lp[i] = lp[i - 1] * lam;

  const float* zsrc = z + ((size_t)(c * B_ + b) * T_ + tile * TT) * D_;

  // stage z tile (coalesced float4)
  for (int i = 0; i < 8; ++i) {
    int fidx = tid + 256 * i;      // 2048 float4
    int row = fidx >> 5, col4 = (fidx & 31) * 4;
    *(float4*)&zf[row][col4] = *(const float4*)(zsrc + (size_t)row * D_ + col4);
  }
  __syncthreads();

  // A-fragments: lane holds A[m=l15][k=8*l4+j], k-chunk ks*32 (cvt f32->bf16 in reg)
  short8 afrag[4];
  const int rowA = w * 16 + l15;
  #pragma unroll
  for (int ks = 0; ks < 4; ++ks) {
    const float* p = &zf[rowA][l4 * 8 + ks * 32];
    float4 a0 = *(const float4*)p;
    float4 a1 = *(const float4*)(p + 4);
    short8 t;
    t[0] = (short)f2bf(a0.x); t[1] = (short)f2bf(a0.y);
    t[2] = (short)f2bf(a0.z); t[3] = (short)f2bf(a0.w);
    t[4] = (short)f2bf(a1.x); t[5] = (short)f2bf(a1.y);
    t[6] = (short)f2bf(a1.z); t[7] = (short)f2bf(a1.w);
    afrag[ks] = t;
  }

  for (int dir = 0; dir < 2; ++dir) {
    const unsigned short* wt = Wt + (size_t)(dir * 8 + c) * D_ * D_;
    const float* bias = (dir ? bb : bf) + (size_t)c * D_;

    f32x4 acc[8];
    #pragma unroll
    for (int f = 0; f < 8; ++f) acc[f] = (f32x4){0.f, 0.f, 0.f, 0.f};

    #pragma unroll
    for (int f = 0; f < 8; ++f) {
      const unsigned short* wb_ = wt + (size_t)(f * 16 + l15) * D_ + l4 * 8;
      #pragma unroll
      for (int ks = 0; ks < 4; ++ks) {
        short8 bfr = *(const short8*)(wb_ + ks * 32);
        acc[f] = __builtin_amdgcn_mfma_f32_16x16x32_bf16(afrag[ks], bfr, acc[f], 0, 0, 0);
      }
    }

    // epilogue: v = sigmoid(logit)*z, thread-local 4-step scan (group = 4 consecutive rows)
    float hseg[8][4];
    #pragma unroll
    for (int f = 0; f < 8; ++f) {
      const int col = f * 16 + l15;
      const float bcol = bias[col];
      float vv[4];
      #pragma unroll
      for (int r = 0; r < 4; ++r) {
        const int row = w * 16 + l4 * 4 + r;
        const float logit = acc[f][r] + bcol;
        const float g = 1.0f / (1.0f + __expf(-logit));
        vv[r] = g * zf[row][col];
      }
      if (dir == 0) {
        float h = 0.f;
        #pragma unroll
        for (int r = 0; r < 4; ++r) { h = fmaf(lam, h, vv[r]); hseg[f][r] = h; }
      } else {
        float h = 0.f;
        #pragma unroll
        for (int r = 3; r >= 0; --r) { h = fmaf(lam, h, vv[r]); hseg[f][r] = h; }
      }
    }

    __syncthreads();   // previous dir's carry-readers done before term rewrite
    #pragma unroll
    for (int f = 0; f < 8; ++f)
      term[w * 4 + l4][f * 16 + l15] = (dir == 0) ? hseg[f][3] : hseg[f][0];
    __syncthreads();

    // 16-group prefix per column (threads 0..127), S = chunk terminal
    if (tid < 128) {
      float tg[16];
      #pragma unroll
      for (int g = 0; g < 16; ++g) tg[g] = term[g][tid];
      float p = 0.f;
      const float l4p = lp[4];
      if (dir == 0) {
        #pragma unroll
        for (int g = 0; g < 16; ++g) { float t = tg[g]; term[g][tid] = p; p = fmaf(l4p, p, t); }
      } else {
        #pragma unroll
        for (int g = 15; g >= 0; --g) { float t = tg[g]; term[g][tid] = p; p = fmaf(l4p, p, t); }
      }
      S[(((size_t)(dir * C_ + c) * B_ + b) * NCH + tile) * D_ + tid] = p;
    }
    __syncthreads();

    // apply group carry, store local_h
    float* dst = out + (size_t)dir * CBTD +
                 ((size_t)(c * B_ + b) * T_ + tile * TT) * D_;
    #pragma unroll
    for (int f = 0; f < 8; ++f) {
      const int col = f * 16 + l15;
      const float carry = term[w * 4 + l4][col];
      #pragma unroll
      for (int r = 0; r < 4; ++r) {
        const int row = w * 16 + l4 * 4 + r;
        const float dec = (dir == 0) ? lp[r + 1] : lp[4 - r];
        dst[(size_t)row * D_ + col] = fmaf(dec, carry, hseg[f][r]);
      }
    }
  }
}

// ---- Phase B: carry prefix across chunks (tiny)
__global__ __launch_bounds__(128)
void prefix_kernel(const float* __restrict__ S, float* __restrict__ Cin) {
  const int bi = blockIdx.x;        // (dir, c, b)
  const int dir = bi >> 5;
  const int c = (bi >> 2) & 7;
  const int b = bi & 3;
  const int e = threadIdx.x;
  const float lam = lam_of(c);
  const float l2lam = (lam > 0.f) ? log2f(lam) : 0.f;
  const float lamL = decay_pow(lam, l2lam, TT);
  const size_t base = ((size_t)(dir * C_ + c) * B_ + b) * NCH * D_ + e;
  float cin = 0.f;
  if (dir == 0) {
    for (int k = 0; k < NCH; ++k) {
      Cin[base + (size_t)k * D_] = cin;
      cin = fmaf(lamL, cin, S[base + (size_t)k * D_]);
    }
  } else {
    for (int k = NCH - 1; k >= 0; --k) {
      Cin[base + (size_t)k * D_] = cin;
      cin = fmaf(lamL, cin, S[base + (size_t)k * D_]);
    }
  }
}

// ---- Phase C: elementwise carry application, h += lam^dist * carry (c=0 skipped)
__global__ __launch_bounds__(256)
void apply_kernel(float* __restrict__ out, const float* __restrict__ Cin) {
  const int bi = blockIdx.x;          // ((dir*C + c)*B + b)*NCH + k
  const int k = bi & (NCH - 1);
  const int b = (bi >> 6) & 3;
  const int c = (bi >> 8) & 7;
  const int dir = bi >> 11;
  if (c == 0) return;                 // lam=0 -> carry always 0
  const float lam = lam_of(c);
  const float l2lam = log2f(lam);
  const int tid = threadIdx.x;
  const int col4 = (tid & 31) * 4;

  const float4 carry = *(const float4*)
      (Cin + (((size_t)(dir * C_ + c) * B_ + b) * NCH + k) * D_ + col4);
  float* base = out + (size_t)dir * CBTD +
                ((size_t)(c * B_ + b) * T_ + k * TT) * D_;
  #pragma unroll
  for (int i = 0; i < 8; ++i) {
    const int row = (tid >> 5) + i * 8;
    const int dist = (dir == 0) ? (row + 1) : (TT - row);
    const float dec = exp2f(l2lam * (float)dist);
    float4 h = *(float4*)(base + (size_t)row * D_ + col4);
    h.x = fmaf(dec, carry.x, h.x);
    h.y = fmaf(dec, carry.y, h.y);
    h.z = fmaf(dec, carry.z, h.z);
    h.w = fmaf(dec, carry.w, h.w);
    *(float4*)(base + (size_t)row * D_ + col4) = h;
  }
}

extern "C" void kernel_launch(void* const* d_in, const int* in_sizes, int n_in,
                              void* d_out, int out_size, void* d_ws, size_t ws_size,
                              hipStream_t stream) {
  const float* z  = (const float*)d_in[0];
  const float* Wf = (const float*)d_in[1];
  const float* bf = (const float*)d_in[2];
  const float* Wb = (const float*)d_in[3];
  const float* bb = (const float*)d_in[4];
  float* out = (float*)d_out;
  float* S   = (float*)d_ws;                      // 2 MB
  float* Cin = S + SSIZE;                         // 2 MB
  unsigned short* Wt = (unsigned short*)(Cin + SSIZE);  // 512 KB bf16

  wcvt_kernel<<<dim3(16), dim3(256), 0, stream>>>(Wf, Wb, Wt);
  gate_mfma_kernel<<<dim3(C_ * B_ * NCH), dim3(256), 0, stream>>>(
      z, Wt, bf, bb, out, S);
  prefix_kernel<<<dim3(2 * C_ * B_), dim3(128), 0, stream>>>(S, Cin);
  apply_kernel<<<dim3(2 * C_ * B_ * NCH), dim3(256), 0, stream>>>(out, Cin);
}